// Round 4
// baseline (1148.322 us; speedup 1.0000x reference)
//
#include <hip/hip_runtime.h>
#include <stdint.h>

#define N_NODES 50000
#define N_EDGES 800000

typedef unsigned int uint32;

// ---------- bf16 helpers ----------
__device__ inline float bflo(uint32 u) { return __builtin_bit_cast(float, u << 16); }
__device__ inline float bfhi(uint32 u) { return __builtin_bit_cast(float, u & 0xffff0000u); }
__device__ inline float bf2f(unsigned short h) { return __builtin_bit_cast(float, (uint32)h << 16); }
__device__ inline unsigned short f2bf(float f) {
    uint32 u = __builtin_bit_cast(uint32, f);
    u += 0x7fffu + ((u >> 16) & 1u);  // RNE
    return (unsigned short)(u >> 16);
}
__device__ inline uint32 pack2(float lo, float hi) {
    return (uint32)f2bf(lo) | ((uint32)f2bf(hi) << 16);
}

// ---------- CSR build ----------
__global__ __launch_bounds__(256) void zero_k(int* p, int n) {
    int i = blockIdx.x * 256 + threadIdx.x;
    if (i < n) p[i] = 0;
}

__global__ __launch_bounds__(256) void count_k(const int* __restrict__ ei, int* __restrict__ cnt) {
    int e = blockIdx.x * 256 + threadIdx.x;
    if (e < N_EDGES) atomicAdd(&cnt[ei[N_EDGES + e]], 1);
}

__global__ __launch_bounds__(1024) void scan_k(int* __restrict__ cnt, int* __restrict__ rowptr) {
    __shared__ int sh[1024];
    const int CH = 49;  // 1024*49 = 50176 >= 50000
    int t = threadIdx.x;
    int base = t * CH;
    int s = 0;
    for (int i = 0; i < CH; i++) {
        int idx = base + i;
        if (idx < N_NODES) s += cnt[idx];
    }
    sh[t] = s;
    __syncthreads();
    for (int d = 1; d < 1024; d <<= 1) {
        int v = (t >= d) ? sh[t - d] : 0;
        __syncthreads();
        sh[t] += v;
        __syncthreads();
    }
    int run = sh[t] - s;
    for (int i = 0; i < CH; i++) {
        int idx = base + i;
        if (idx < N_NODES) {
            int v = cnt[idx];
            rowptr[idx] = run;
            cnt[idx] = run;  // cursor copy
            run += v;
        }
    }
    if (t == 1023) rowptr[N_NODES] = sh[1023];
}

__global__ __launch_bounds__(256) void fill_k(const int* __restrict__ ei, int* __restrict__ cursor,
                                              int* __restrict__ csr) {
    int e = blockIdx.x * 256 + threadIdx.x;
    if (e < N_EDGES) {
        int d = ei[N_EDGES + e];
        int p = atomicAdd(&cursor[d], 1);
        csr[p] = ei[e];  // src
    }
}

// ---------- weight prep: W fp32 [k][n] -> Whi/Wlo bf16 [n][k] (hi+lo split) ----------
__global__ __launch_bounds__(256) void wprep_k(const float* __restrict__ W,
                                               unsigned short* __restrict__ Whi,
                                               unsigned short* __restrict__ Wlo) {
    int idx = blockIdx.x * 256 + threadIdx.x;  // 262144
    int k = idx >> 9, n = idx & 511;
    float w = W[idx];
    unsigned short hi = f2bf(w);
    float lo = w - bf2f(hi);
    Whi[n * 512 + k] = hi;
    Wlo[n * 512 + k] = f2bf(lo);
}

// ---------- x fp32 -> bf16 packed ----------
__global__ __launch_bounds__(256) void xconv_k(const float* __restrict__ x, uint32* __restrict__ xb) {
    int i = blockIdx.x * 256 + threadIdx.x;  // 12.8M
    float2 v = ((const float2*)x)[i];
    xb[i] = pack2(v.x, v.y);
}

// ---------- aggregation v2: h[dst] = sum_{src} feat[src] + (1+eps)*feat[dst] ----------
// One node per block. Each wave reads FULL 1KB rows (uint4 = 16B/lane x 64 lanes),
// waves stripe the edge list (stride 4), fp32 partials reduced via SoA LDS
// (4B lane stride -> conflict-free).
__global__ __launch_bounds__(256) void agg_k(const uint4* __restrict__ xin,
                                             const int* __restrict__ rowptr,
                                             const int* __restrict__ csr,
                                             const float* __restrict__ eps,
                                             uint4* __restrict__ hout) {
    __shared__ float red[8 * 3 * 64];  // [feat][wave-1][lane]
    int node = blockIdx.x;
    int w = threadIdx.x >> 6, lane = threadIdx.x & 63;
    int beg = rowptr[node], end = rowptr[node + 1];
    float a0 = 0.f, a1 = 0.f, a2 = 0.f, a3 = 0.f, a4 = 0.f, a5 = 0.f, a6 = 0.f, a7 = 0.f;
    int e = beg + w;
    for (; e + 4 < end; e += 8) {  // two edges per iter: e, e+4
        int s0 = csr[e], s1 = csr[e + 4];
        uint4 q0 = xin[(size_t)s0 * 64 + lane];
        uint4 q1 = xin[(size_t)s1 * 64 + lane];
        a0 += bflo(q0.x) + bflo(q1.x);
        a1 += bfhi(q0.x) + bfhi(q1.x);
        a2 += bflo(q0.y) + bflo(q1.y);
        a3 += bfhi(q0.y) + bfhi(q1.y);
        a4 += bflo(q0.z) + bflo(q1.z);
        a5 += bfhi(q0.z) + bfhi(q1.z);
        a6 += bflo(q0.w) + bflo(q1.w);
        a7 += bfhi(q0.w) + bfhi(q1.w);
    }
    if (e < end) {
        int s0 = csr[e];
        uint4 q0 = xin[(size_t)s0 * 64 + lane];
        a0 += bflo(q0.x); a1 += bfhi(q0.x);
        a2 += bflo(q0.y); a3 += bfhi(q0.y);
        a4 += bflo(q0.z); a5 += bfhi(q0.z);
        a6 += bflo(q0.w); a7 += bfhi(q0.w);
    }
    if (w > 0) {
        int base = (w - 1) * 64 + lane;
        red[0 * 192 + base] = a0;
        red[1 * 192 + base] = a1;
        red[2 * 192 + base] = a2;
        red[3 * 192 + base] = a3;
        red[4 * 192 + base] = a4;
        red[5 * 192 + base] = a5;
        red[6 * 192 + base] = a6;
        red[7 * 192 + base] = a7;
    }
    __syncthreads();
    if (w == 0) {
        uint4 qs = xin[(size_t)node * 64 + lane];  // self row (issued early; latency hidden by LDS reduce)
        float ep = 1.0f + eps[0];
#pragma unroll
        for (int p = 0; p < 3; p++) {
            int base = p * 64 + lane;
            a0 += red[0 * 192 + base];
            a1 += red[1 * 192 + base];
            a2 += red[2 * 192 + base];
            a3 += red[3 * 192 + base];
            a4 += red[4 * 192 + base];
            a5 += red[5 * 192 + base];
            a6 += red[6 * 192 + base];
            a7 += red[7 * 192 + base];
        }
        a0 = fmaf(ep, bflo(qs.x), a0);
        a1 = fmaf(ep, bfhi(qs.x), a1);
        a2 = fmaf(ep, bflo(qs.y), a2);
        a3 = fmaf(ep, bfhi(qs.y), a3);
        a4 = fmaf(ep, bflo(qs.z), a4);
        a5 = fmaf(ep, bfhi(qs.z), a5);
        a6 = fmaf(ep, bflo(qs.w), a6);
        a7 = fmaf(ep, bfhi(qs.w), a7);
        uint4 o;
        o.x = pack2(a0, a1);
        o.y = pack2(a2, a3);
        o.z = pack2(a4, a5);
        o.w = pack2(a6, a7);
        hout[(size_t)node * 64 + lane] = o;
    }
}

// ---------- GEMM: relu(A[M,512](bf16) @ W[512,512] + b(fp32)) ----------
// W given as bf16 [n][k] (Whi, + Wlo if SPLIT). Out: bf16 (outB) or fp32 (outF).
typedef __bf16 bf16x8 __attribute__((ext_vector_type(8)));
typedef float f32x4 __attribute__((ext_vector_type(4)));

template <bool SPLIT, bool F32OUT>
__global__ __launch_bounds__(256) void gemm_k(const unsigned short* __restrict__ A,
                                              const unsigned short* __restrict__ Whi,
                                              const unsigned short* __restrict__ Wlo,
                                              const float* __restrict__ bias,
                                              unsigned short* __restrict__ outB,
                                              float* __restrict__ outF, int M) {
    constexpr int K = 512, N = 512, BK = 32, TM = 128;
    __shared__ unsigned short lds_a[TM * BK];
    __shared__ unsigned short lds_bh[TM * BK];
    __shared__ unsigned short lds_bl[SPLIT ? TM * BK : 16];
    const int t = threadIdx.x;
    const int w = t >> 6, lane = t & 63;
    const int wrow = w >> 1, wcol = w & 1;
    const int m0 = blockIdx.y * TM;
    const int n0 = blockIdx.x * TM;

    int r0 = t >> 2, cc = (t & 3) * 8;
    int r1 = 64 + r0;
    int am0 = m0 + r0; am0 = am0 < M ? am0 : M - 1;
    int am1 = m0 + r1; am1 = am1 < M ? am1 : M - 1;
    const unsigned short* ag0 = A + (size_t)am0 * K + cc;
    const unsigned short* ag1 = A + (size_t)am1 * K + cc;
    const unsigned short* bh0 = Whi + (size_t)(n0 + r0) * K + cc;
    const unsigned short* bh1 = Whi + (size_t)(n0 + r1) * K + cc;
    const unsigned short* bl0 = Wlo + (size_t)(n0 + r0) * K + cc;
    const unsigned short* bl1 = Wlo + (size_t)(n0 + r1) * K + cc;

    f32x4 acc[4][4] = {};
    const int quad = lane >> 4, l15 = lane & 15;
    const int arow = wrow * 64 + l15;
    const int brow = wcol * 64 + l15;

    for (int k0 = 0; k0 < K; k0 += BK) {
        uint4 va0 = *(const uint4*)(ag0 + k0);
        uint4 va1 = *(const uint4*)(ag1 + k0);
        uint4 vh0 = *(const uint4*)(bh0 + k0);
        uint4 vh1 = *(const uint4*)(bh1 + k0);
        uint4 vl0, vl1;
        if (SPLIT) {
            vl0 = *(const uint4*)(bl0 + k0);
            vl1 = *(const uint4*)(bl1 + k0);
        }
        __syncthreads();  // previous iteration's LDS reads complete
        *(uint4*)&lds_a[r0 * BK + cc] = va0;
        *(uint4*)&lds_a[r1 * BK + cc] = va1;
        *(uint4*)&lds_bh[r0 * BK + cc] = vh0;
        *(uint4*)&lds_bh[r1 * BK + cc] = vh1;
        if (SPLIT) {
            *(uint4*)&lds_bl[r0 * BK + cc] = vl0;
            *(uint4*)&lds_bl[r1 * BK + cc] = vl1;
        }
        __syncthreads();
        bf16x8 af[4], bh[4], bl[4];
#pragma unroll
        for (int i = 0; i < 4; i++)
            af[i] = *(const bf16x8*)&lds_a[(arow + i * 16) * BK + quad * 8];
#pragma unroll
        for (int j = 0; j < 4; j++)
            bh[j] = *(const bf16x8*)&lds_bh[(brow + j * 16) * BK + quad * 8];
        if (SPLIT) {
#pragma unroll
            for (int j = 0; j < 4; j++)
                bl[j] = *(const bf16x8*)&lds_bl[(brow + j * 16) * BK + quad * 8];
        }
#pragma unroll
        for (int i = 0; i < 4; i++)
#pragma unroll
            for (int j = 0; j < 4; j++) {
                acc[i][j] = __builtin_amdgcn_mfma_f32_16x16x32_bf16(af[i], bh[j], acc[i][j], 0, 0, 0);
                if (SPLIT)
                    acc[i][j] = __builtin_amdgcn_mfma_f32_16x16x32_bf16(af[i], bl[j], acc[i][j], 0, 0, 0);
            }
    }

    // epilogue: C/D mapping col(n) = lane&15, row(m) = quad*4 + reg
#pragma unroll
    for (int j = 0; j < 4; j++) {
        int n = n0 + wcol * 64 + j * 16 + l15;
        float bv = bias[n];
#pragma unroll
        for (int i = 0; i < 4; i++) {
            int mbase = m0 + wrow * 64 + i * 16 + quad * 4;
#pragma unroll
            for (int r = 0; r < 4; r++) {
                int m = mbase + r;
                if (m < M) {
                    float v = fmaxf(acc[i][j][r] + bv, 0.0f);
                    if (F32OUT) outF[(size_t)m * N + n] = v;
                    else        outB[(size_t)m * N + n] = f2bf(v);
                }
            }
        }
    }
}

// ---------- L2 normalize (bf16 in/out, in-place safe): one wave per node ----------
__global__ __launch_bounds__(256) void l2norm_k(const uint32* __restrict__ z, uint32* __restrict__ out) {
    int node = blockIdx.x * 4 + (threadIdx.x >> 6);
    int lane = threadIdx.x & 63;
    const uint4* zp = (const uint4*)(z + (size_t)node * 256);
    uint4 q = zp[lane];
    float f0 = bflo(q.x), f1 = bfhi(q.x), f2 = bflo(q.y), f3 = bfhi(q.y);
    float f4 = bflo(q.z), f5 = bfhi(q.z), f6 = bflo(q.w), f7 = bfhi(q.w);
    float ss = f0 * f0 + f1 * f1 + f2 * f2 + f3 * f3 + f4 * f4 + f5 * f5 + f6 * f6 + f7 * f7;
#pragma unroll
    for (int off = 32; off > 0; off >>= 1) ss += __shfl_xor(ss, off);
    float inv = 1.0f / fmaxf(sqrtf(ss), 1e-12f);
    uint4 o;
    o.x = pack2(f0 * inv, f1 * inv);
    o.y = pack2(f2 * inv, f3 * inv);
    o.z = pack2(f4 * inv, f5 * inv);
    o.w = pack2(f6 * inv, f7 * inv);
    ((uint4*)(out + (size_t)node * 256))[lane] = o;
}

// ---------- softmax over 512 classes (fp32): logits already in d_out; write probs ----------
__global__ __launch_bounds__(256) void softmax_k(const float* __restrict__ logits,
                                                 float* __restrict__ probs) {
    int node = blockIdx.x * 4 + (threadIdx.x >> 6);
    int lane = threadIdx.x & 63;
    const float4* zp = (const float4*)(logits + (size_t)node * 512);
    float4 q0 = zp[lane * 2], q1 = zp[lane * 2 + 1];
    float f[8] = {q0.x, q0.y, q0.z, q0.w, q1.x, q1.y, q1.z, q1.w};
    float m = f[0];
#pragma unroll
    for (int i = 1; i < 8; i++) m = fmaxf(m, f[i]);
#pragma unroll
    for (int off = 32; off > 0; off >>= 1) m = fmaxf(m, __shfl_xor(m, off));
    float e[8], s = 0.f;
#pragma unroll
    for (int i = 0; i < 8; i++) { e[i] = __expf(f[i] - m); s += e[i]; }
#pragma unroll
    for (int off = 32; off > 0; off >>= 1) s += __shfl_xor(s, off);
    float inv = 1.0f / s;
    float4* pp = (float4*)(probs + (size_t)node * 512);
    pp[lane * 2]     = make_float4(e[0] * inv, e[1] * inv, e[2] * inv, e[3] * inv);
    pp[lane * 2 + 1] = make_float4(e[4] * inv, e[5] * inv, e[6] * inv, e[7] * inv);
}

// ---------- host launch ----------
extern "C" void kernel_launch(void* const* d_in, const int* in_sizes, int n_in,
                              void* d_out, int out_size, void* d_ws, size_t ws_size,
                              hipStream_t stream) {
    (void)in_sizes; (void)n_in; (void)out_size; (void)ws_size;
    const float* x = (const float*)d_in[0];
    const int* ei = (const int*)d_in[1];
    const float* W1 = (const float*)d_in[2];
    const float* b1 = (const float*)d_in[3];
    const float* e1 = (const float*)d_in[4];
    const float* W2 = (const float*)d_in[5];
    const float* b2 = (const float*)d_in[6];
    const float* e2 = (const float*)d_in[7];
    const float* W3 = (const float*)d_in[8];
    const float* b3 = (const float*)d_in[9];
    const float* e3 = (const float*)d_in[10];
    float* out = (float*)d_out;                      // logits[50000*512] ++ probs[50000*512]
    float* out_logits = out;
    float* out_probs = out + (size_t)N_NODES * 512;

    // workspace layout (~109 MB)
    char* ws = (char*)d_ws;
    int* rowptr = (int*)ws;                          // 50048 ints
    int* cursor = rowptr + 50048;                    // 50048 ints
    int* csr = cursor + 50048;                       // 800000 ints
    unsigned short* Wsp = (unsigned short*)(csr + N_EDGES);  // 3 layers x (hi 256K + lo 256K) shorts
    unsigned short* featA = Wsp + 3 * 524288;        // 25.6M shorts (51.2 MB)
    unsigned short* featB = featA + (size_t)N_NODES * 512;  // 25.6M shorts

    // CSR build
    zero_k<<<196, 256, 0, stream>>>(cursor, N_NODES);
    count_k<<<(N_EDGES + 255) / 256, 256, 0, stream>>>(ei, cursor);
    scan_k<<<1, 1024, 0, stream>>>(cursor, rowptr);
    fill_k<<<(N_EDGES + 255) / 256, 256, 0, stream>>>(ei, cursor, csr);

    // weight prep (hi/lo bf16, transposed to [n][k])
    wprep_k<<<1024, 256, 0, stream>>>(W1, Wsp,           Wsp + 262144);
    wprep_k<<<1024, 256, 0, stream>>>(W2, Wsp + 524288,  Wsp + 786432);
    wprep_k<<<1024, 256, 0, stream>>>(W3, Wsp + 1048576, Wsp + 1310720);

    // x -> bf16
    xconv_k<<<50000, 256, 0, stream>>>(x, (uint32*)featB);

    dim3 ggrid(4, (N_NODES + 127) / 128);

    // layer 1
    agg_k<<<N_NODES, 256, 0, stream>>>((const uint4*)featB, rowptr, csr, e1, (uint4*)featA);
    gemm_k<false, false><<<ggrid, 256, 0, stream>>>(featA, Wsp, Wsp + 262144, b1, featB, nullptr, N_NODES);
    l2norm_k<<<N_NODES / 4, 256, 0, stream>>>((const uint32*)featB, (uint32*)featB);
    // layer 2
    agg_k<<<N_NODES, 256, 0, stream>>>((const uint4*)featB, rowptr, csr, e2, (uint4*)featA);
    gemm_k<false, false><<<ggrid, 256, 0, stream>>>(featA, Wsp + 524288, Wsp + 786432, b2, featB, nullptr, N_NODES);
    l2norm_k<<<N_NODES / 4, 256, 0, stream>>>((const uint32*)featB, (uint32*)featB);
    // layer 3: split-precision GEMM, fp32 logits straight to d_out
    agg_k<<<N_NODES, 256, 0, stream>>>((const uint4*)featB, rowptr, csr, e3, (uint4*)featA);
    gemm_k<true, true><<<ggrid, 256, 0, stream>>>(featA, Wsp + 1048576, Wsp + 1310720, b3, nullptr, out_logits, N_NODES);
    // softmax -> probs
    softmax_k<<<N_NODES / 4, 256, 0, stream>>>(out_logits, out_probs);
}

// Round 5
// 1145.847 us; speedup vs baseline: 1.0022x; 1.0022x over previous
//
#include <hip/hip_runtime.h>
#include <stdint.h>

#define N_NODES 50000
#define N_EDGES 800000

typedef unsigned int uint32;

// ---------- bf16 helpers ----------
__device__ inline float bflo(uint32 u) { return __builtin_bit_cast(float, u << 16); }
__device__ inline float bfhi(uint32 u) { return __builtin_bit_cast(float, u & 0xffff0000u); }
__device__ inline float bf2f(unsigned short h) { return __builtin_bit_cast(float, (uint32)h << 16); }
__device__ inline unsigned short f2bf(float f) {
    uint32 u = __builtin_bit_cast(uint32, f);
    u += 0x7fffu + ((u >> 16) & 1u);  // RNE
    return (unsigned short)(u >> 16);
}
__device__ inline uint32 pack2(float lo, float hi) {
    return (uint32)f2bf(lo) | ((uint32)f2bf(hi) << 16);
}

// ---------- CSR build ----------
__global__ __launch_bounds__(256) void zero_k(int* p, int n) {
    int i = blockIdx.x * 256 + threadIdx.x;
    if (i < n) p[i] = 0;
}

__global__ __launch_bounds__(256) void count_k(const int* __restrict__ ei, int* __restrict__ cnt) {
    int e = blockIdx.x * 256 + threadIdx.x;
    if (e < N_EDGES) atomicAdd(&cnt[ei[N_EDGES + e]], 1);
}

__global__ __launch_bounds__(1024) void scan_k(int* __restrict__ cnt, int* __restrict__ rowptr) {
    __shared__ int sh[1024];
    const int CH = 49;  // 1024*49 = 50176 >= 50000
    int t = threadIdx.x;
    int base = t * CH;
    int s = 0;
    for (int i = 0; i < CH; i++) {
        int idx = base + i;
        if (idx < N_NODES) s += cnt[idx];
    }
    sh[t] = s;
    __syncthreads();
    for (int d = 1; d < 1024; d <<= 1) {
        int v = (t >= d) ? sh[t - d] : 0;
        __syncthreads();
        sh[t] += v;
        __syncthreads();
    }
    int run = sh[t] - s;
    for (int i = 0; i < CH; i++) {
        int idx = base + i;
        if (idx < N_NODES) {
            int v = cnt[idx];
            rowptr[idx] = run;
            cnt[idx] = run;  // cursor copy
            run += v;
        }
    }
    if (t == 1023) rowptr[N_NODES] = sh[1023];
}

__global__ __launch_bounds__(256) void fill_k(const int* __restrict__ ei, int* __restrict__ cursor,
                                              int* __restrict__ csr) {
    int e = blockIdx.x * 256 + threadIdx.x;
    if (e < N_EDGES) {
        int d = ei[N_EDGES + e];
        int p = atomicAdd(&cursor[d], 1);
        csr[p] = ei[e];  // src
    }
}

// ---------- weight prep: W fp32 [k][n] -> Whi/Wlo bf16 [n][k] (hi+lo split) ----------
__global__ __launch_bounds__(256) void wprep_k(const float* __restrict__ W,
                                               unsigned short* __restrict__ Whi,
                                               unsigned short* __restrict__ Wlo) {
    int idx = blockIdx.x * 256 + threadIdx.x;  // 262144
    int k = idx >> 9, n = idx & 511;
    float w = W[idx];
    unsigned short hi = f2bf(w);
    float lo = w - bf2f(hi);
    Whi[n * 512 + k] = hi;
    Wlo[n * 512 + k] = f2bf(lo);
}

// ---------- x fp32 -> bf16 packed ----------
__global__ __launch_bounds__(256) void xconv_k(const float* __restrict__ x, uint32* __restrict__ xb) {
    int i = blockIdx.x * 256 + threadIdx.x;  // 12.8M
    float2 v = ((const float2*)x)[i];
    xb[i] = pack2(v.x, v.y);
}

// ---------- per-node inverse L2 norm of bf16 feature row ----------
__global__ __launch_bounds__(256) void norm_k(const uint4* __restrict__ z, float* __restrict__ invn) {
    int node = blockIdx.x * 4 + (threadIdx.x >> 6);
    int lane = threadIdx.x & 63;
    uint4 q = z[(size_t)node * 64 + lane];
    float f0 = bflo(q.x), f1 = bfhi(q.x), f2 = bflo(q.y), f3 = bfhi(q.y);
    float f4 = bflo(q.z), f5 = bfhi(q.z), f6 = bflo(q.w), f7 = bfhi(q.w);
    float ss = f0 * f0 + f1 * f1 + f2 * f2 + f3 * f3 + f4 * f4 + f5 * f5 + f6 * f6 + f7 * f7;
#pragma unroll
    for (int off = 32; off > 0; off >>= 1) ss += __shfl_xor(ss, off);
    if (lane == 0) invn[node] = 1.0f / fmaxf(sqrtf(ss), 1e-12f);
}

// ---------- aggregation v3: wave-per-node, fused L2-normalize of inputs ----------
// h[dst] = sum_{src} s(src)*feat[src] + (1+eps)*s(dst)*feat[dst], s = invn (SCALED) or 1.
// Each wave owns one node: reads full 1KB rows (uint4 x 64 lanes), unroll-4 edges
// for 4 independent row-loads in flight. No LDS, no barriers.
template <bool SCALED>
__global__ __launch_bounds__(256) void agg_k(const uint4* __restrict__ xin,
                                             const int* __restrict__ rowptr,
                                             const int* __restrict__ csr,
                                             const float* __restrict__ eps,
                                             const float* __restrict__ invn,
                                             uint4* __restrict__ hout) {
    int node = blockIdx.x * 4 + (threadIdx.x >> 6);
    int lane = threadIdx.x & 63;
    int beg = rowptr[node], end = rowptr[node + 1];
    float a0 = 0.f, a1 = 0.f, a2 = 0.f, a3 = 0.f, a4 = 0.f, a5 = 0.f, a6 = 0.f, a7 = 0.f;
    int e = beg;
    for (; e + 4 <= end; e += 4) {
        int s0 = csr[e], s1 = csr[e + 1], s2 = csr[e + 2], s3 = csr[e + 3];
        uint4 q0 = xin[(size_t)s0 * 64 + lane];
        uint4 q1 = xin[(size_t)s1 * 64 + lane];
        uint4 q2 = xin[(size_t)s2 * 64 + lane];
        uint4 q3 = xin[(size_t)s3 * 64 + lane];
        float w0 = SCALED ? invn[s0] : 1.0f;
        float w1 = SCALED ? invn[s1] : 1.0f;
        float w2 = SCALED ? invn[s2] : 1.0f;
        float w3 = SCALED ? invn[s3] : 1.0f;
        a0 = fmaf(w0, bflo(q0.x), fmaf(w1, bflo(q1.x), fmaf(w2, bflo(q2.x), fmaf(w3, bflo(q3.x), a0))));
        a1 = fmaf(w0, bfhi(q0.x), fmaf(w1, bfhi(q1.x), fmaf(w2, bfhi(q2.x), fmaf(w3, bfhi(q3.x), a1))));
        a2 = fmaf(w0, bflo(q0.y), fmaf(w1, bflo(q1.y), fmaf(w2, bflo(q2.y), fmaf(w3, bflo(q3.y), a2))));
        a3 = fmaf(w0, bfhi(q0.y), fmaf(w1, bfhi(q1.y), fmaf(w2, bfhi(q2.y), fmaf(w3, bfhi(q3.y), a3))));
        a4 = fmaf(w0, bflo(q0.z), fmaf(w1, bflo(q1.z), fmaf(w2, bflo(q2.z), fmaf(w3, bflo(q3.z), a4))));
        a5 = fmaf(w0, bfhi(q0.z), fmaf(w1, bfhi(q1.z), fmaf(w2, bfhi(q2.z), fmaf(w3, bfhi(q3.z), a5))));
        a6 = fmaf(w0, bflo(q0.w), fmaf(w1, bflo(q1.w), fmaf(w2, bflo(q2.w), fmaf(w3, bflo(q3.w), a6))));
        a7 = fmaf(w0, bfhi(q0.w), fmaf(w1, bfhi(q1.w), fmaf(w2, bfhi(q2.w), fmaf(w3, bfhi(q3.w), a7))));
    }
    for (; e < end; ++e) {
        int s0 = csr[e];
        uint4 q0 = xin[(size_t)s0 * 64 + lane];
        float w0 = SCALED ? invn[s0] : 1.0f;
        a0 = fmaf(w0, bflo(q0.x), a0); a1 = fmaf(w0, bfhi(q0.x), a1);
        a2 = fmaf(w0, bflo(q0.y), a2); a3 = fmaf(w0, bfhi(q0.y), a3);
        a4 = fmaf(w0, bflo(q0.z), a4); a5 = fmaf(w0, bfhi(q0.z), a5);
        a6 = fmaf(w0, bflo(q0.w), a6); a7 = fmaf(w0, bfhi(q0.w), a7);
    }
    uint4 qs = xin[(size_t)node * 64 + lane];
    float ws = (1.0f + eps[0]) * (SCALED ? invn[node] : 1.0f);
    a0 = fmaf(ws, bflo(qs.x), a0); a1 = fmaf(ws, bfhi(qs.x), a1);
    a2 = fmaf(ws, bflo(qs.y), a2); a3 = fmaf(ws, bfhi(qs.y), a3);
    a4 = fmaf(ws, bflo(qs.z), a4); a5 = fmaf(ws, bfhi(qs.z), a5);
    a6 = fmaf(ws, bflo(qs.w), a6); a7 = fmaf(ws, bfhi(qs.w), a7);
    uint4 o;
    o.x = pack2(a0, a1);
    o.y = pack2(a2, a3);
    o.z = pack2(a4, a5);
    o.w = pack2(a6, a7);
    hout[(size_t)node * 64 + lane] = o;
}

// ---------- GEMM: relu(A[M,512](bf16) @ W[512,512] + b(fp32)) ----------
// async global->LDS staging (width 16); W as bf16 [n][k] (Whi, + Wlo if SPLIT).
typedef __bf16 bf16x8 __attribute__((ext_vector_type(8)));
typedef float f32x4 __attribute__((ext_vector_type(4)));

__device__ inline void async16(const void* g, void* l) {
    __builtin_amdgcn_global_load_lds((const __attribute__((address_space(1))) void*)g,
                                     (__attribute__((address_space(3))) void*)l, 16, 0, 0);
}

template <bool SPLIT, bool F32OUT>
__global__ __launch_bounds__(256) void gemm_k(const unsigned short* __restrict__ A,
                                              const unsigned short* __restrict__ Whi,
                                              const unsigned short* __restrict__ Wlo,
                                              const float* __restrict__ bias,
                                              unsigned short* __restrict__ outB,
                                              float* __restrict__ outF, int M) {
    constexpr int K = 512, N = 512, BK = 32, TM = 128;
    __shared__ unsigned short lds_a[TM * BK];
    __shared__ unsigned short lds_bh[TM * BK];
    __shared__ unsigned short lds_bl[SPLIT ? TM * BK : 16];
    const int t = threadIdx.x;
    const int w = t >> 6, lane = t & 63;
    const int wrow = w >> 1, wcol = w & 1;
    const int m0 = blockIdx.y * TM;
    const int n0 = blockIdx.x * TM;

    // staging: wave w, lane l covers row w*16 + (l>>2), cols (l&3)*8 .. +8
    // LDS offset = row*64B + (l&3)*16B = w*1024B + l*16B  -> wave-uniform base + lane*16
    int r0 = w * 16 + (lane >> 2), cc = (lane & 3) * 8;
    int r1 = 64 + r0;
    int am0 = m0 + r0; am0 = am0 < M ? am0 : M - 1;  // clamp; dup rows discarded in epilogue
    int am1 = m0 + r1; am1 = am1 < M ? am1 : M - 1;
    const unsigned short* ag0 = A + (size_t)am0 * K + cc;
    const unsigned short* ag1 = A + (size_t)am1 * K + cc;
    const unsigned short* bh0 = Whi + (size_t)(n0 + r0) * K + cc;
    const unsigned short* bh1 = Whi + (size_t)(n0 + r1) * K + cc;
    const unsigned short* bl0 = Wlo + (size_t)(n0 + r0) * K + cc;
    const unsigned short* bl1 = Wlo + (size_t)(n0 + r1) * K + cc;
    unsigned short* la0 = lds_a + w * 512;
    unsigned short* la1 = lds_a + 2048 + w * 512;
    unsigned short* lh0 = lds_bh + w * 512;
    unsigned short* lh1 = lds_bh + 2048 + w * 512;
    unsigned short* ll0 = lds_bl + w * 512;
    unsigned short* ll1 = lds_bl + 2048 + w * 512;

    f32x4 acc[4][4] = {};
    const int quad = lane >> 4, l15 = lane & 15;
    const int arow = wrow * 64 + l15;
    const int brow = wcol * 64 + l15;

    for (int k0 = 0; k0 < K; k0 += BK) {
        __syncthreads();  // all waves done reading previous tile
        async16(ag0 + k0, la0);
        async16(ag1 + k0, la1);
        async16(bh0 + k0, lh0);
        async16(bh1 + k0, lh1);
        if (SPLIT) {
            async16(bl0 + k0, ll0);
            async16(bl1 + k0, ll1);
        }
        __syncthreads();  // staging landed (compiler drains vmcnt before barrier)
        bf16x8 af[4], bh[4], bl[4];
#pragma unroll
        for (int i = 0; i < 4; i++)
            af[i] = *(const bf16x8*)&lds_a[(arow + i * 16) * BK + quad * 8];
#pragma unroll
        for (int j = 0; j < 4; j++)
            bh[j] = *(const bf16x8*)&lds_bh[(brow + j * 16) * BK + quad * 8];
        if (SPLIT) {
#pragma unroll
            for (int j = 0; j < 4; j++)
                bl[j] = *(const bf16x8*)&lds_bl[(brow + j * 16) * BK + quad * 8];
        }
#pragma unroll
        for (int i = 0; i < 4; i++)
#pragma unroll
            for (int j = 0; j < 4; j++) {
                acc[i][j] = __builtin_amdgcn_mfma_f32_16x16x32_bf16(af[i], bh[j], acc[i][j], 0, 0, 0);
                if (SPLIT)
                    acc[i][j] = __builtin_amdgcn_mfma_f32_16x16x32_bf16(af[i], bl[j], acc[i][j], 0, 0, 0);
            }
    }

    // epilogue: C/D mapping col(n) = lane&15, row(m) = quad*4 + reg
#pragma unroll
    for (int j = 0; j < 4; j++) {
        int n = n0 + wcol * 64 + j * 16 + l15;
        float bv = bias[n];
#pragma unroll
        for (int i = 0; i < 4; i++) {
            int mbase = m0 + wrow * 64 + i * 16 + quad * 4;
#pragma unroll
            for (int r = 0; r < 4; r++) {
                int m = mbase + r;
                if (m < M) {
                    float v = fmaxf(acc[i][j][r] + bv, 0.0f);
                    if (F32OUT) outF[(size_t)m * N + n] = v;
                    else        outB[(size_t)m * N + n] = f2bf(v);
                }
            }
        }
    }
}

// ---------- softmax over 512 classes (fp32): logits already in d_out; write probs ----------
__global__ __launch_bounds__(256) void softmax_k(const float* __restrict__ logits,
                                                 float* __restrict__ probs) {
    int node = blockIdx.x * 4 + (threadIdx.x >> 6);
    int lane = threadIdx.x & 63;
    const float4* zp = (const float4*)(logits + (size_t)node * 512);
    float4 q0 = zp[lane * 2], q1 = zp[lane * 2 + 1];
    float f[8] = {q0.x, q0.y, q0.z, q0.w, q1.x, q1.y, q1.z, q1.w};
    float m = f[0];
#pragma unroll
    for (int i = 1; i < 8; i++) m = fmaxf(m, f[i]);
#pragma unroll
    for (int off = 32; off > 0; off >>= 1) m = fmaxf(m, __shfl_xor(m, off));
    float e[8], s = 0.f;
#pragma unroll
    for (int i = 0; i < 8; i++) { e[i] = __expf(f[i] - m); s += e[i]; }
#pragma unroll
    for (int off = 32; off > 0; off >>= 1) s += __shfl_xor(s, off);
    float inv = 1.0f / s;
    float4* pp = (float4*)(probs + (size_t)node * 512);
    pp[lane * 2]     = make_float4(e[0] * inv, e[1] * inv, e[2] * inv, e[3] * inv);
    pp[lane * 2 + 1] = make_float4(e[4] * inv, e[5] * inv, e[6] * inv, e[7] * inv);
}

// ---------- host launch ----------
extern "C" void kernel_launch(void* const* d_in, const int* in_sizes, int n_in,
                              void* d_out, int out_size, void* d_ws, size_t ws_size,
                              hipStream_t stream) {
    (void)in_sizes; (void)n_in; (void)out_size; (void)ws_size;
    const float* x = (const float*)d_in[0];
    const int* ei = (const int*)d_in[1];
    const float* W1 = (const float*)d_in[2];
    const float* b1 = (const float*)d_in[3];
    const float* e1 = (const float*)d_in[4];
    const float* W2 = (const float*)d_in[5];
    const float* b2 = (const float*)d_in[6];
    const float* e2 = (const float*)d_in[7];
    const float* W3 = (const float*)d_in[8];
    const float* b3 = (const float*)d_in[9];
    const float* e3 = (const float*)d_in[10];
    float* out = (float*)d_out;                      // logits[50000*512] ++ probs[50000*512]
    float* out_logits = out;
    float* out_probs = out + (size_t)N_NODES * 512;

    // workspace layout (~109 MB)
    char* ws = (char*)d_ws;
    int* rowptr = (int*)ws;                          // 50048 ints
    int* cursor = rowptr + 50048;                    // 50048 ints
    int* csr = cursor + 50048;                       // 800000 ints
    float* invn = (float*)(csr + N_EDGES);           // 50048 floats
    unsigned short* Wsp = (unsigned short*)(invn + 50048);  // 3 layers x (hi 256K + lo 256K) shorts
    unsigned short* featA = Wsp + 3 * 524288;        // 25.6M shorts (51.2 MB)
    unsigned short* featB = featA + (size_t)N_NODES * 512;  // 25.6M shorts

    // CSR build
    zero_k<<<196, 256, 0, stream>>>(cursor, N_NODES);
    count_k<<<(N_EDGES + 255) / 256, 256, 0, stream>>>(ei, cursor);
    scan_k<<<1, 1024, 0, stream>>>(cursor, rowptr);
    fill_k<<<(N_EDGES + 255) / 256, 256, 0, stream>>>(ei, cursor, csr);

    // weight prep (hi/lo bf16, transposed to [n][k])
    wprep_k<<<1024, 256, 0, stream>>>(W1, Wsp,           Wsp + 262144);
    wprep_k<<<1024, 256, 0, stream>>>(W2, Wsp + 524288,  Wsp + 786432);
    wprep_k<<<1024, 256, 0, stream>>>(W3, Wsp + 1048576, Wsp + 1310720);

    // x -> bf16
    xconv_k<<<50000, 256, 0, stream>>>(x, (uint32*)featB);

    dim3 ggrid(4, (N_NODES + 127) / 128);

    // layer 1
    agg_k<false><<<12500, 256, 0, stream>>>((const uint4*)featB, rowptr, csr, e1, nullptr, (uint4*)featA);
    gemm_k<false, false><<<ggrid, 256, 0, stream>>>(featA, Wsp, Wsp + 262144, b1, featB, nullptr, N_NODES);
    // layer 2 (l2-normalize fused into agg via invn)
    norm_k<<<12500, 256, 0, stream>>>((const uint4*)featB, invn);
    agg_k<true><<<12500, 256, 0, stream>>>((const uint4*)featB, rowptr, csr, e2, invn, (uint4*)featA);
    gemm_k<false, false><<<ggrid, 256, 0, stream>>>(featA, Wsp + 524288, Wsp + 786432, b2, featB, nullptr, N_NODES);
    // layer 3 (fused normalize; split-precision GEMM, fp32 logits straight to d_out)
    norm_k<<<12500, 256, 0, stream>>>((const uint4*)featB, invn);
    agg_k<true><<<12500, 256, 0, stream>>>((const uint4*)featB, rowptr, csr, e3, invn, (uint4*)featA);
    gemm_k<true, true><<<ggrid, 256, 0, stream>>>(featA, Wsp + 1048576, Wsp + 1310720, b3, nullptr, out_logits, N_NODES);
    // softmax -> probs
    softmax_k<<<N_NODES / 4, 256, 0, stream>>>(out_logits, out_probs);
}

// Round 6
// 1034.017 us; speedup vs baseline: 1.1105x; 1.1082x over previous
//
#include <hip/hip_runtime.h>
#include <stdint.h>

#define N_NODES 50000
#define N_EDGES 800000

typedef unsigned int uint32;

// ---------- bf16 helpers ----------
__device__ inline float bflo(uint32 u) { return __builtin_bit_cast(float, u << 16); }
__device__ inline float bfhi(uint32 u) { return __builtin_bit_cast(float, u & 0xffff0000u); }
__device__ inline float bf2f(unsigned short h) { return __builtin_bit_cast(float, (uint32)h << 16); }
__device__ inline unsigned short f2bf(float f) {
    uint32 u = __builtin_bit_cast(uint32, f);
    u += 0x7fffu + ((u >> 16) & 1u);  // RNE
    return (unsigned short)(u >> 16);
}
__device__ inline uint32 pack2(float lo, float hi) {
    return (uint32)f2bf(lo) | ((uint32)f2bf(hi) << 16);
}

// ---------- CSR build ----------
__global__ __launch_bounds__(256) void zero_k(int* p, int n) {
    int i = blockIdx.x * 256 + threadIdx.x;
    if (i < n) p[i] = 0;
}

__global__ __launch_bounds__(256) void count_k(const int* __restrict__ ei, int* __restrict__ cnt) {
    int e = blockIdx.x * 256 + threadIdx.x;
    if (e < N_EDGES) atomicAdd(&cnt[ei[N_EDGES + e]], 1);
}

// hierarchical coalesced scan: blocksum -> bscan -> scatter  (replaces 128us scan_k)
#define NB 196  // 196*256 = 50176 >= 50000

__global__ __launch_bounds__(256) void blocksum_k(const int* __restrict__ cnt, int* __restrict__ bsum) {
    int i = blockIdx.x * 256 + threadIdx.x;
    int v = (i < N_NODES) ? cnt[i] : 0;
#pragma unroll
    for (int off = 32; off > 0; off >>= 1) v += __shfl_down(v, off);
    __shared__ int sh[4];
    int w = threadIdx.x >> 6, lane = threadIdx.x & 63;
    if (lane == 0) sh[w] = v;
    __syncthreads();
    if (threadIdx.x == 0) bsum[blockIdx.x] = sh[0] + sh[1] + sh[2] + sh[3];
}

__global__ __launch_bounds__(256) void bscan_k(const int* __restrict__ bsum, int* __restrict__ bpre,
                                               int* __restrict__ rowptr) {
    __shared__ int sh[256];
    int t = threadIdx.x;
    int v = (t < NB) ? bsum[t] : 0;
    sh[t] = v;
    __syncthreads();
    for (int d = 1; d < 256; d <<= 1) {
        int u = (t >= d) ? sh[t - d] : 0;
        __syncthreads();
        sh[t] += u;
        __syncthreads();
    }
    if (t < NB) bpre[t] = sh[t] - v;          // exclusive block prefix
    if (t == NB - 1) rowptr[N_NODES] = sh[t]; // total = N_EDGES
}

__global__ __launch_bounds__(256) void scatter_k(int* __restrict__ cnt, const int* __restrict__ bpre,
                                                 int* __restrict__ rowptr) {
    int b = blockIdx.x, t = threadIdx.x, i = b * 256 + t;
    int w = t >> 6, lane = t & 63;
    int myv = (i < N_NODES) ? cnt[i] : 0;
    int v = myv;
#pragma unroll
    for (int d = 1; d < 64; d <<= 1) {
        int u = __shfl_up(v, d);
        if (lane >= d) v += u;
    }
    __shared__ int wt[4];
    if (lane == 63) wt[w] = v;
    __syncthreads();
    int off = bpre[b];
    for (int k = 0; k < w; k++) off += wt[k];
    int excl = v - myv + off;
    if (i < N_NODES) {
        rowptr[i] = excl;
        cnt[i] = excl;  // becomes cursor (in-place safe: myv read before write)
    }
}

__global__ __launch_bounds__(256) void fill_k(const int* __restrict__ ei, int* __restrict__ cursor,
                                              int* __restrict__ csr) {
    int e = blockIdx.x * 256 + threadIdx.x;
    if (e < N_EDGES) {
        int d = ei[N_EDGES + e];
        int p = atomicAdd(&cursor[d], 1);
        csr[p] = ei[e];  // src
    }
}

// ---------- weight prep: W fp32 [k][n] -> Whi/Wlo bf16 [n][k] (hi+lo split) ----------
__global__ __launch_bounds__(256) void wprep_k(const float* __restrict__ W,
                                               unsigned short* __restrict__ Whi,
                                               unsigned short* __restrict__ Wlo) {
    int idx = blockIdx.x * 256 + threadIdx.x;  // 262144
    int k = idx >> 9, n = idx & 511;
    float w = W[idx];
    unsigned short hi = f2bf(w);
    float lo = w - bf2f(hi);
    Whi[n * 512 + k] = hi;
    Wlo[n * 512 + k] = f2bf(lo);
}

// ---------- x fp32 -> bf16 packed ----------
__global__ __launch_bounds__(256) void xconv_k(const float* __restrict__ x, uint32* __restrict__ xb) {
    int i = blockIdx.x * 256 + threadIdx.x;  // 12.8M
    float2 v = ((const float2*)x)[i];
    xb[i] = pack2(v.x, v.y);
}

// ---------- per-node inverse L2 norm of bf16 feature row ----------
__global__ __launch_bounds__(256) void norm_k(const uint4* __restrict__ z, float* __restrict__ invn) {
    int node = blockIdx.x * 4 + (threadIdx.x >> 6);
    int lane = threadIdx.x & 63;
    uint4 q = z[(size_t)node * 64 + lane];
    float f0 = bflo(q.x), f1 = bfhi(q.x), f2 = bflo(q.y), f3 = bfhi(q.y);
    float f4 = bflo(q.z), f5 = bfhi(q.z), f6 = bflo(q.w), f7 = bfhi(q.w);
    float ss = f0 * f0 + f1 * f1 + f2 * f2 + f3 * f3 + f4 * f4 + f5 * f5 + f6 * f6 + f7 * f7;
#pragma unroll
    for (int off = 32; off > 0; off >>= 1) ss += __shfl_xor(ss, off);
    if (lane == 0) invn[node] = 1.0f / fmaxf(sqrtf(ss), 1e-12f);
}

// ---------- aggregation: wave-per-node, fused L2-normalize of inputs ----------
template <bool SCALED>
__global__ __launch_bounds__(256) void agg_k(const uint4* __restrict__ xin,
                                             const int* __restrict__ rowptr,
                                             const int* __restrict__ csr,
                                             const float* __restrict__ eps,
                                             const float* __restrict__ invn,
                                             uint4* __restrict__ hout) {
    int node = blockIdx.x * 4 + (threadIdx.x >> 6);
    int lane = threadIdx.x & 63;
    int beg = rowptr[node], end = rowptr[node + 1];
    float a0 = 0.f, a1 = 0.f, a2 = 0.f, a3 = 0.f, a4 = 0.f, a5 = 0.f, a6 = 0.f, a7 = 0.f;
    int e = beg;
    for (; e + 4 <= end; e += 4) {
        int s0 = csr[e], s1 = csr[e + 1], s2 = csr[e + 2], s3 = csr[e + 3];
        uint4 q0 = xin[(size_t)s0 * 64 + lane];
        uint4 q1 = xin[(size_t)s1 * 64 + lane];
        uint4 q2 = xin[(size_t)s2 * 64 + lane];
        uint4 q3 = xin[(size_t)s3 * 64 + lane];
        float w0 = SCALED ? invn[s0] : 1.0f;
        float w1 = SCALED ? invn[s1] : 1.0f;
        float w2 = SCALED ? invn[s2] : 1.0f;
        float w3 = SCALED ? invn[s3] : 1.0f;
        a0 = fmaf(w0, bflo(q0.x), fmaf(w1, bflo(q1.x), fmaf(w2, bflo(q2.x), fmaf(w3, bflo(q3.x), a0))));
        a1 = fmaf(w0, bfhi(q0.x), fmaf(w1, bfhi(q1.x), fmaf(w2, bfhi(q2.x), fmaf(w3, bfhi(q3.x), a1))));
        a2 = fmaf(w0, bflo(q0.y), fmaf(w1, bflo(q1.y), fmaf(w2, bflo(q2.y), fmaf(w3, bflo(q3.y), a2))));
        a3 = fmaf(w0, bfhi(q0.y), fmaf(w1, bfhi(q1.y), fmaf(w2, bfhi(q2.y), fmaf(w3, bfhi(q3.y), a3))));
        a4 = fmaf(w0, bflo(q0.z), fmaf(w1, bflo(q1.z), fmaf(w2, bflo(q2.z), fmaf(w3, bflo(q3.z), a4))));
        a5 = fmaf(w0, bfhi(q0.z), fmaf(w1, bfhi(q1.z), fmaf(w2, bfhi(q2.z), fmaf(w3, bfhi(q3.z), a5))));
        a6 = fmaf(w0, bflo(q0.w), fmaf(w1, bflo(q1.w), fmaf(w2, bflo(q2.w), fmaf(w3, bflo(q3.w), a6))));
        a7 = fmaf(w0, bfhi(q0.w), fmaf(w1, bfhi(q1.w), fmaf(w2, bfhi(q2.w), fmaf(w3, bfhi(q3.w), a7))));
    }
    for (; e < end; ++e) {
        int s0 = csr[e];
        uint4 q0 = xin[(size_t)s0 * 64 + lane];
        float w0 = SCALED ? invn[s0] : 1.0f;
        a0 = fmaf(w0, bflo(q0.x), a0); a1 = fmaf(w0, bfhi(q0.x), a1);
        a2 = fmaf(w0, bflo(q0.y), a2); a3 = fmaf(w0, bfhi(q0.y), a3);
        a4 = fmaf(w0, bflo(q0.z), a4); a5 = fmaf(w0, bfhi(q0.z), a5);
        a6 = fmaf(w0, bflo(q0.w), a6); a7 = fmaf(w0, bfhi(q0.w), a7);
    }
    uint4 qs = xin[(size_t)node * 64 + lane];
    float ws = (1.0f + eps[0]) * (SCALED ? invn[node] : 1.0f);
    a0 = fmaf(ws, bflo(qs.x), a0); a1 = fmaf(ws, bfhi(qs.x), a1);
    a2 = fmaf(ws, bflo(qs.y), a2); a3 = fmaf(ws, bfhi(qs.y), a3);
    a4 = fmaf(ws, bflo(qs.z), a4); a5 = fmaf(ws, bfhi(qs.z), a5);
    a6 = fmaf(ws, bflo(qs.w), a6); a7 = fmaf(ws, bfhi(qs.w), a7);
    uint4 o;
    o.x = pack2(a0, a1);
    o.y = pack2(a2, a3);
    o.z = pack2(a4, a5);
    o.w = pack2(a6, a7);
    hout[(size_t)node * 64 + lane] = o;
}

// ---------- GEMM: relu(A[M,512](bf16) @ W[512,512] + b(fp32)) ----------
typedef __bf16 bf16x8 __attribute__((ext_vector_type(8)));
typedef float f32x4 __attribute__((ext_vector_type(4)));

__device__ inline void async16(const void* g, void* l) {
    __builtin_amdgcn_global_load_lds((const __attribute__((address_space(1))) void*)g,
                                     (__attribute__((address_space(3))) void*)l, 16, 0, 0);
}

template <bool SPLIT, bool F32OUT>
__global__ __launch_bounds__(256) void gemm_k(const unsigned short* __restrict__ A,
                                              const unsigned short* __restrict__ Whi,
                                              const unsigned short* __restrict__ Wlo,
                                              const float* __restrict__ bias,
                                              unsigned short* __restrict__ outB,
                                              float* __restrict__ outF, int M) {
    constexpr int K = 512, N = 512, BK = 32, TM = 128;
    __shared__ unsigned short lds_a[TM * BK];
    __shared__ unsigned short lds_bh[TM * BK];
    __shared__ unsigned short lds_bl[SPLIT ? TM * BK : 16];
    const int t = threadIdx.x;
    const int w = t >> 6, lane = t & 63;
    const int wrow = w >> 1, wcol = w & 1;
    const int m0 = blockIdx.y * TM;
    const int n0 = blockIdx.x * TM;

    int r0 = w * 16 + (lane >> 2), cc = (lane & 3) * 8;
    int r1 = 64 + r0;
    int am0 = m0 + r0; am0 = am0 < M ? am0 : M - 1;
    int am1 = m0 + r1; am1 = am1 < M ? am1 : M - 1;
    const unsigned short* ag0 = A + (size_t)am0 * K + cc;
    const unsigned short* ag1 = A + (size_t)am1 * K + cc;
    const unsigned short* bh0 = Whi + (size_t)(n0 + r0) * K + cc;
    const unsigned short* bh1 = Whi + (size_t)(n0 + r1) * K + cc;
    const unsigned short* bl0 = Wlo + (size_t)(n0 + r0) * K + cc;
    const unsigned short* bl1 = Wlo + (size_t)(n0 + r1) * K + cc;
    unsigned short* la0 = lds_a + w * 512;
    unsigned short* la1 = lds_a + 2048 + w * 512;
    unsigned short* lh0 = lds_bh + w * 512;
    unsigned short* lh1 = lds_bh + 2048 + w * 512;
    unsigned short* ll0 = lds_bl + w * 512;
    unsigned short* ll1 = lds_bl + 2048 + w * 512;

    f32x4 acc[4][4] = {};
    const int quad = lane >> 4, l15 = lane & 15;
    const int arow = wrow * 64 + l15;
    const int brow = wcol * 64 + l15;

    for (int k0 = 0; k0 < K; k0 += BK) {
        __syncthreads();
        async16(ag0 + k0, la0);
        async16(ag1 + k0, la1);
        async16(bh0 + k0, lh0);
        async16(bh1 + k0, lh1);
        if (SPLIT) {
            async16(bl0 + k0, ll0);
            async16(bl1 + k0, ll1);
        }
        __syncthreads();
        bf16x8 af[4], bh[4], bl[4];
#pragma unroll
        for (int i = 0; i < 4; i++)
            af[i] = *(const bf16x8*)&lds_a[(arow + i * 16) * BK + quad * 8];
#pragma unroll
        for (int j = 0; j < 4; j++)
            bh[j] = *(const bf16x8*)&lds_bh[(brow + j * 16) * BK + quad * 8];
        if (SPLIT) {
#pragma unroll
            for (int j = 0; j < 4; j++)
                bl[j] = *(const bf16x8*)&lds_bl[(brow + j * 16) * BK + quad * 8];
        }
#pragma unroll
        for (int i = 0; i < 4; i++)
#pragma unroll
            for (int j = 0; j < 4; j++) {
                acc[i][j] = __builtin_amdgcn_mfma_f32_16x16x32_bf16(af[i], bh[j], acc[i][j], 0, 0, 0);
                if (SPLIT)
                    acc[i][j] = __builtin_amdgcn_mfma_f32_16x16x32_bf16(af[i], bl[j], acc[i][j], 0, 0, 0);
            }
    }

#pragma unroll
    for (int j = 0; j < 4; j++) {
        int n = n0 + wcol * 64 + j * 16 + l15;
        float bv = bias[n];
#pragma unroll
        for (int i = 0; i < 4; i++) {
            int mbase = m0 + wrow * 64 + i * 16 + quad * 4;
#pragma unroll
            for (int r = 0; r < 4; r++) {
                int m = mbase + r;
                if (m < M) {
                    float v = fmaxf(acc[i][j][r] + bv, 0.0f);
                    if (F32OUT) outF[(size_t)m * N + n] = v;
                    else        outB[(size_t)m * N + n] = f2bf(v);
                }
            }
        }
    }
}

// ---------- softmax over 512 classes (fp32) ----------
__global__ __launch_bounds__(256) void softmax_k(const float* __restrict__ logits,
                                                 float* __restrict__ probs) {
    int node = blockIdx.x * 4 + (threadIdx.x >> 6);
    int lane = threadIdx.x & 63;
    const float4* zp = (const float4*)(logits + (size_t)node * 512);
    float4 q0 = zp[lane * 2], q1 = zp[lane * 2 + 1];
    float f[8] = {q0.x, q0.y, q0.z, q0.w, q1.x, q1.y, q1.z, q1.w};
    float m = f[0];
#pragma unroll
    for (int i = 1; i < 8; i++) m = fmaxf(m, f[i]);
#pragma unroll
    for (int off = 32; off > 0; off >>= 1) m = fmaxf(m, __shfl_xor(m, off));
    float e[8], s = 0.f;
#pragma unroll
    for (int i = 0; i < 8; i++) { e[i] = __expf(f[i] - m); s += e[i]; }
#pragma unroll
    for (int off = 32; off > 0; off >>= 1) s += __shfl_xor(s, off);
    float inv = 1.0f / s;
    float4* pp = (float4*)(probs + (size_t)node * 512);
    pp[lane * 2]     = make_float4(e[0] * inv, e[1] * inv, e[2] * inv, e[3] * inv);
    pp[lane * 2 + 1] = make_float4(e[4] * inv, e[5] * inv, e[6] * inv, e[7] * inv);
}

// ---------- host launch ----------
extern "C" void kernel_launch(void* const* d_in, const int* in_sizes, int n_in,
                              void* d_out, int out_size, void* d_ws, size_t ws_size,
                              hipStream_t stream) {
    (void)in_sizes; (void)n_in; (void)out_size; (void)ws_size;
    const float* x = (const float*)d_in[0];
    const int* ei = (const int*)d_in[1];
    const float* W1 = (const float*)d_in[2];
    const float* b1 = (const float*)d_in[3];
    const float* e1 = (const float*)d_in[4];
    const float* W2 = (const float*)d_in[5];
    const float* b2 = (const float*)d_in[6];
    const float* e2 = (const float*)d_in[7];
    const float* W3 = (const float*)d_in[8];
    const float* b3 = (const float*)d_in[9];
    const float* e3 = (const float*)d_in[10];
    float* out = (float*)d_out;
    float* out_logits = out;
    float* out_probs = out + (size_t)N_NODES * 512;

    // workspace layout (~109 MB)
    char* ws = (char*)d_ws;
    int* rowptr = (int*)ws;                          // 50048 ints
    int* cursor = rowptr + 50048;                    // 50048 ints (counts -> cursor)
    int* csr = cursor + 50048;                       // 800000 ints
    float* invn = (float*)(csr + N_EDGES);           // 50048 floats
    int* bsum = (int*)(invn + 50048);                // 256 ints
    int* bpre = bsum + 256;                          // 256 ints
    unsigned short* Wsp = (unsigned short*)(bpre + 256);
    unsigned short* featA = Wsp + 3 * 524288;        // 25.6M shorts (51.2 MB)
    unsigned short* featB = featA + (size_t)N_NODES * 512;

    // CSR build (hierarchical coalesced scan)
    zero_k<<<196, 256, 0, stream>>>(cursor, N_NODES);
    count_k<<<(N_EDGES + 255) / 256, 256, 0, stream>>>(ei, cursor);
    blocksum_k<<<NB, 256, 0, stream>>>(cursor, bsum);
    bscan_k<<<1, 256, 0, stream>>>(bsum, bpre, rowptr);
    scatter_k<<<NB, 256, 0, stream>>>(cursor, bpre, rowptr);
    fill_k<<<(N_EDGES + 255) / 256, 256, 0, stream>>>(ei, cursor, csr);

    // weight prep (hi/lo bf16, transposed to [n][k])
    wprep_k<<<1024, 256, 0, stream>>>(W1, Wsp,           Wsp + 262144);
    wprep_k<<<1024, 256, 0, stream>>>(W2, Wsp + 524288,  Wsp + 786432);
    wprep_k<<<1024, 256, 0, stream>>>(W3, Wsp + 1048576, Wsp + 1310720);

    // x -> bf16
    xconv_k<<<50000, 256, 0, stream>>>(x, (uint32*)featB);

    dim3 ggrid(4, (N_NODES + 127) / 128);

    // layer 1
    agg_k<false><<<12500, 256, 0, stream>>>((const uint4*)featB, rowptr, csr, e1, nullptr, (uint4*)featA);
    gemm_k<false, false><<<ggrid, 256, 0, stream>>>(featA, Wsp, Wsp + 262144, b1, featB, nullptr, N_NODES);
    // layer 2 (l2-normalize fused into agg via invn)
    norm_k<<<12500, 256, 0, stream>>>((const uint4*)featB, invn);
    agg_k<true><<<12500, 256, 0, stream>>>((const uint4*)featB, rowptr, csr, e2, invn, (uint4*)featA);
    gemm_k<false, false><<<ggrid, 256, 0, stream>>>(featA, Wsp + 524288, Wsp + 786432, b2, featB, nullptr, N_NODES);
    // layer 3 (fused normalize; split-precision GEMM, fp32 logits straight to d_out)
    norm_k<<<12500, 256, 0, stream>>>((const uint4*)featB, invn);
    agg_k<true><<<12500, 256, 0, stream>>>((const uint4*)featB, rowptr, csr, e3, invn, (uint4*)featA);
    gemm_k<true, true><<<ggrid, 256, 0, stream>>>(featA, Wsp + 1048576, Wsp + 1310720, b3, nullptr, out_logits, N_NODES);
    // softmax -> probs
    softmax_k<<<N_NODES / 4, 256, 0, stream>>>(out_logits, out_probs);
}